// Round 5
// baseline (112.247 us; speedup 1.0000x reference)
//
#include <hip/hip_runtime.h>

#define B_ 16
#define N_ 64
#define C_ 128
#define H_ 64
#define W_ 64
#define HW_ (H_ * W_)
#define OUT_CH_ 256
#define MAX_GRID_ 16
#define SCALE_ 0.125f

__device__ __forceinline__ unsigned short f2bf(float f) {
  unsigned int u = __float_as_uint(f);
  u = (u + 0x7fffu + ((u >> 16) & 1u)) >> 16;  // round-to-nearest-even
  return (unsigned short)u;
}

// ---------------------------------------------------------------------------
// Kernel 1: z [B, C, HW] fp32 -> zf [B, HW, C] bf16 (128x128 tiles), and
// (blockIdx.y==16 slab) W [OUT_CH, C] -> Wt [C, OUT_CH] fp32.
// ---------------------------------------------------------------------------
__global__ __launch_bounds__(256) void transpose_kernel(
    const float* __restrict__ z, const float* __restrict__ Wm,
    unsigned short* __restrict__ zf, float* __restrict__ Wt) {
  __shared__ unsigned short tile[128 * 129];
  const int t = threadIdx.x;

  if (blockIdx.y == 16) {   // W-transpose slab: 32 blocks, one 32x32 tile each
    float* ft = (float*)tile;               // 32 x 33
    int x  = blockIdx.x;                    // 0..31
    int ot = x & 7, ct = x >> 3;
    int j = t & 31, i0 = t >> 5;
#pragma unroll
    for (int k = 0; k < 4; ++k) {
      int i = i0 + k * 8;
      ft[i * 33 + j] = Wm[(size_t)(ot * 32 + i) * C_ + ct * 32 + j];
    }
    __syncthreads();
#pragma unroll
    for (int k = 0; k < 4; ++k) {
      int i = i0 + k * 8;
      Wt[(size_t)(ct * 32 + i) * OUT_CH_ + ot * 32 + j] = ft[j * 33 + i];
    }
    return;
  }

  const int b  = blockIdx.y;
  const int pt = blockIdx.x;  // HW tile, 0..31
  const float* zb = z + (size_t)b * C_ * HW_;
#pragma unroll
  for (int iter = 0; iter < 16; ++iter) {
    int idx = iter * 256 + t;        // 0..4095
    int c   = idx >> 5;              // 0..127
    int p4  = (idx & 31) << 2;       // 0,4,...,124
    float4 v = *(const float4*)(zb + (size_t)c * HW_ + pt * 128 + p4);
    tile[(p4 + 0) * 129 + c] = f2bf(v.x);
    tile[(p4 + 1) * 129 + c] = f2bf(v.y);
    tile[(p4 + 2) * 129 + c] = f2bf(v.z);
    tile[(p4 + 3) * 129 + c] = f2bf(v.w);
  }
  __syncthreads();

  unsigned short* zfb = zf + (size_t)b * HW_ * C_;
#pragma unroll
  for (int iter = 0; iter < 8; ++iter) {
    int idx = iter * 256 + t;        // 0..2047
    int p   = idx >> 4;              // 0..127
    int k8  = (idx & 15) << 3;       // 0,8,...,120
    const unsigned short* src = &tile[p * 129 + k8];
    uint4 u;
    u.x = (unsigned int)src[0] | ((unsigned int)src[1] << 16);
    u.y = (unsigned int)src[2] | ((unsigned int)src[3] << 16);
    u.z = (unsigned int)src[4] | ((unsigned int)src[5] << 16);
    u.w = (unsigned int)src[6] | ((unsigned int)src[7] << 16);
    *(uint4*)(zfb + (size_t)(pt * 128 + p) * C_ + k8) = u;
  }
}

// ---------------------------------------------------------------------------
// Kernel 2: gather. One wave per (roi, gy) row. Block = 128 thr (2 waves).
// gx loop is a COMPILE-TIME 16-iteration fully-unrolled loop with masked
// weights: iterations past gw get weight 0 and an address clamped to gx=0
// (L2-hit dup load). Fixed trip count + independent addresses let the
// compiler hoist all 64 corner loads and stage the vmcnt waits, collapsing
// ~9 serial memory round-trips into ~1.
// ---------------------------------------------------------------------------
__global__ __launch_bounds__(128) void gather_kernel(
    const unsigned short* __restrict__ zf,   // [B, HW, C] bf16
    const float* __restrict__ boxes,         // [B, N, 4]
    float* __restrict__ partial)             // [B*N, 16, C] fp32
{
  int bid  = blockIdx.x;        // 0..8191
  int xcd  = bid & 7;
  int slot = bid >> 3;          // 0..1023
  int img  = xcd + ((slot >> 9) << 3);   // 0..15  (image -> XCD class)
  int s    = slot & 511;
  int roi  = img * N_ + (s >> 3);
  int t    = threadIdx.x;
  int gy   = ((s & 7) << 1) + (t >> 6);
  int co   = (t & 63) << 1;     // channel offset (pairs)

  float4 bx = ((const float4*)boxes)[roi];
  float x1 = bx.x * SCALE_ - 0.5f;
  float y1 = bx.y * SCALE_ - 0.5f;
  float roi_w = bx.z * SCALE_ - 0.5f - x1;
  float roi_h = bx.w * SCALE_ - 0.5f - y1;
  float gwf = fminf(fmaxf(ceilf(roi_w), 1.0f), (float)MAX_GRID_);
  float ghf = fminf(fmaxf(ceilf(roi_h), 1.0f), (float)MAX_GRID_);
  int gw = (int)gwf;
  int gh = (int)ghf;
  if (gy >= gh) return;       // wave-uniform

  float stepx = roi_w / gwf;
  float stepy = roi_h / ghf;

  float sy = y1 + ((float)gy + 0.5f) * stepy;
  float wy = (sy > -1.0f && sy < (float)H_) ? 1.0f : 0.0f;
  float cy = fmaxf(sy, 0.0f);
  int yl = (int)cy;
  yl = yl < (H_ - 1) ? yl : (H_ - 1);
  int yh = (yl + 1) < (H_ - 1) ? (yl + 1) : (H_ - 1);
  if (yl >= H_ - 1) cy = (float)yl;
  float fy = cy - (float)yl;
  float hy = 1.0f - fy;

  const unsigned short* zb = zf + (size_t)(roi >> 6) * (HW_ * C_);
  const unsigned short* rowl = zb + (size_t)yl * W_ * C_ + co;
  const unsigned short* rowh = zb + (size_t)yh * W_ * C_ + co;

  float acc0 = 0.0f, acc1 = 0.0f;
#pragma unroll
  for (int gx = 0; gx < MAX_GRID_; ++gx) {
    float valid = (gx < gw) ? 1.0f : 0.0f;
    int gxe = (gx < gw) ? gx : 0;     // clamped -> dup of a cached line
    float sx = x1 + ((float)gxe + 0.5f) * stepx;
    float wx = (sx > -1.0f && sx < (float)W_) ? 1.0f : 0.0f;
    float cx = fmaxf(sx, 0.0f);
    int xl = (int)cx;
    xl = xl < (W_ - 1) ? xl : (W_ - 1);
    int xh = (xl + 1) < (W_ - 1) ? (xl + 1) : (W_ - 1);
    if (xl >= W_ - 1) cx = (float)xl;
    float fx = cx - (float)xl;
    float hx = 1.0f - fx;

    float m   = wy * wx * valid;
    float w11 = hy * hx * m, w12 = hy * fx * m;
    float w21 = fy * hx * m, w22 = fy * fx * m;
    unsigned int v11 = *(const unsigned int*)(rowl + (xl << 7));
    unsigned int v12 = *(const unsigned int*)(rowl + (xh << 7));
    unsigned int v21 = *(const unsigned int*)(rowh + (xl << 7));
    unsigned int v22 = *(const unsigned int*)(rowh + (xh << 7));

    acc0 += w11 * __uint_as_float(v11 << 16)
          + w12 * __uint_as_float(v12 << 16)
          + w21 * __uint_as_float(v21 << 16)
          + w22 * __uint_as_float(v22 << 16);
    acc1 += w11 * __uint_as_float(v11 & 0xffff0000u)
          + w12 * __uint_as_float(v12 & 0xffff0000u)
          + w21 * __uint_as_float(v21 & 0xffff0000u)
          + w22 * __uint_as_float(v22 & 0xffff0000u);
  }

  *(float2*)(partial + (size_t)(roi * MAX_GRID_ + gy) * C_ + co)
      = make_float2(acc0, acc1);
}

// ---------------------------------------------------------------------------
// Kernel 3: final. 4 ROIs per block (256 blocks): reduce gy rows into LDS
// feats, then Linear with Wt amortized over 4 ROIs (coalesced reads).
// ---------------------------------------------------------------------------
__global__ __launch_bounds__(256) void final_kernel(
    const float* __restrict__ partial,  // [B*N, 16, C]
    const float* __restrict__ boxes,
    const float* __restrict__ Wt,       // [C, OUT_CH]
    const float* __restrict__ bias,
    float* __restrict__ out)            // [B*N, OUT_CH]
{
  int rbase = blockIdx.x << 2;
  int t  = threadIdx.x;
  int c  = t & 127;
  int r2 = t >> 7;   // 0..1

  __shared__ float feat[4][128];
#pragma unroll
  for (int rr = 0; rr < 2; ++rr) {
    int r   = r2 * 2 + rr;
    int roi = rbase + r;
    float4 bx = ((const float4*)boxes)[roi];
    float gwf = fminf(fmaxf(ceilf((bx.z - bx.x) * SCALE_), 1.0f), (float)MAX_GRID_);
    float ghf = fminf(fmaxf(ceilf((bx.w - bx.y) * SCALE_), 1.0f), (float)MAX_GRID_);
    int gh = (int)ghf;
    float s = 0.0f;
    for (int gy = 0; gy < gh; ++gy)
      s += partial[(size_t)(roi * MAX_GRID_ + gy) * C_ + c];
    feat[r][c] = s * (1.0f / (ghf * gwf));
  }
  __syncthreads();

  float bv = bias[t];
  float a0 = 0.0f, a1 = 0.0f, a2 = 0.0f, a3 = 0.0f;
#pragma unroll 4
  for (int k = 0; k < C_; ++k) {
    float w = Wt[(size_t)k * OUT_CH_ + t];
    a0 += feat[0][k] * w;
    a1 += feat[1][k] * w;
    a2 += feat[2][k] * w;
    a3 += feat[3][k] * w;
  }
  out[(size_t)(rbase + 0) * OUT_CH_ + t] = a0 + bv;
  out[(size_t)(rbase + 1) * OUT_CH_ + t] = a1 + bv;
  out[(size_t)(rbase + 2) * OUT_CH_ + t] = a2 + bv;
  out[(size_t)(rbase + 3) * OUT_CH_ + t] = a3 + bv;
}

extern "C" void kernel_launch(void* const* d_in, const int* in_sizes, int n_in,
                              void* d_out, int out_size, void* d_ws, size_t ws_size,
                              hipStream_t stream) {
  const float* z     = (const float*)d_in[0];  // [B,C,H,W]
  const float* boxes = (const float*)d_in[1];  // [B,N,4]
  const float* Wm    = (const float*)d_in[2];  // [OUT_CH,C]
  const float* bias  = (const float*)d_in[3];  // [OUT_CH]
  float* out = (float*)d_out;

  char* ws = (char*)d_ws;
  unsigned short* zf = (unsigned short*)ws;                       // 16.78 MB
  float* partial = (float*)(ws + (size_t)B_ * HW_ * C_ * 2);      // 8.39 MB
  float* Wt = (float*)(ws + (size_t)B_ * HW_ * C_ * 2
                          + (size_t)B_ * N_ * MAX_GRID_ * C_ * 4);// 128 KB

  transpose_kernel<<<dim3(HW_ / 128, B_ + 1), 256, 0, stream>>>(z, Wm, zf, Wt);
  gather_kernel<<<B_ * N_ * (MAX_GRID_ / 2), 128, 0, stream>>>(zf, boxes, partial);
  final_kernel<<<B_ * N_ / 4, 256, 0, stream>>>(partial, boxes, Wt, bias, out);
}

// Round 6
// 99.368 us; speedup vs baseline: 1.1296x; 1.1296x over previous
//
#include <hip/hip_runtime.h>

#define B_ 16
#define N_ 64
#define C_ 128
#define H_ 64
#define W_ 64
#define HW_ (H_ * W_)
#define OUT_CH_ 256
#define MAX_GRID_ 16
#define SCALE_ 0.125f

__device__ __forceinline__ unsigned short f2bf(float f) {
  unsigned int u = __float_as_uint(f);
  u = (u + 0x7fffu + ((u >> 16) & 1u)) >> 16;  // round-to-nearest-even
  return (unsigned short)u;
}

// ---------------------------------------------------------------------------
// Kernel 1: z [B, C, HW] fp32 -> zf [B, HW, C] bf16 (128x128 tiles), and
// (blockIdx.y==16 slab) W [OUT_CH, C] -> Wt [C, OUT_CH] fp32.
// ---------------------------------------------------------------------------
__global__ __launch_bounds__(256) void transpose_kernel(
    const float* __restrict__ z, const float* __restrict__ Wm,
    unsigned short* __restrict__ zf, float* __restrict__ Wt) {
  __shared__ unsigned short tile[128 * 129];
  const int t = threadIdx.x;

  if (blockIdx.y == 16) {   // W-transpose slab: 32 blocks, one 32x32 tile each
    float* ft = (float*)tile;               // 32 x 33
    int x  = blockIdx.x;                    // 0..31
    int ot = x & 7, ct = x >> 3;
    int j = t & 31, i0 = t >> 5;
#pragma unroll
    for (int k = 0; k < 4; ++k) {
      int i = i0 + k * 8;
      ft[i * 33 + j] = Wm[(size_t)(ot * 32 + i) * C_ + ct * 32 + j];
    }
    __syncthreads();
#pragma unroll
    for (int k = 0; k < 4; ++k) {
      int i = i0 + k * 8;
      Wt[(size_t)(ct * 32 + i) * OUT_CH_ + ot * 32 + j] = ft[j * 33 + i];
    }
    return;
  }

  const int b  = blockIdx.y;
  const int pt = blockIdx.x;  // HW tile, 0..31
  const float* zb = z + (size_t)b * C_ * HW_;
#pragma unroll
  for (int iter = 0; iter < 16; ++iter) {
    int idx = iter * 256 + t;        // 0..4095
    int c   = idx >> 5;              // 0..127
    int p4  = (idx & 31) << 2;       // 0,4,...,124
    float4 v = *(const float4*)(zb + (size_t)c * HW_ + pt * 128 + p4);
    tile[(p4 + 0) * 129 + c] = f2bf(v.x);
    tile[(p4 + 1) * 129 + c] = f2bf(v.y);
    tile[(p4 + 2) * 129 + c] = f2bf(v.z);
    tile[(p4 + 3) * 129 + c] = f2bf(v.w);
  }
  __syncthreads();

  unsigned short* zfb = zf + (size_t)b * HW_ * C_;
#pragma unroll
  for (int iter = 0; iter < 8; ++iter) {
    int idx = iter * 256 + t;        // 0..2047
    int p   = idx >> 4;              // 0..127
    int k8  = (idx & 15) << 3;       // 0,8,...,120
    const unsigned short* src = &tile[p * 129 + k8];
    uint4 u;
    u.x = (unsigned int)src[0] | ((unsigned int)src[1] << 16);
    u.y = (unsigned int)src[2] | ((unsigned int)src[3] << 16);
    u.z = (unsigned int)src[4] | ((unsigned int)src[5] << 16);
    u.w = (unsigned int)src[6] | ((unsigned int)src[7] << 16);
    *(uint4*)(zfb + (size_t)(pt * 128 + p) * C_ + k8) = u;
  }
}

// ---------------------------------------------------------------------------
// Kernel 2: fused ROI-align + reduce + Linear. One block (512 thr = 8 waves)
// per ROI; wave w handles gy rows {w, w+8} (max 32, typical ~9-18 serial
// samples -> balanced). Lanes = 64 channel pairs (full 128-ch coalesced
// burst per corner). Branchless gx loop. Epilogue: 8-way LDS reduce, then
// split-K Linear using all 512 threads. XCD swizzle keeps each image's
// 1 MB zf slice on one XCD's L2.
// ---------------------------------------------------------------------------
__global__ __launch_bounds__(512) void roi_fused_kernel(
    const unsigned short* __restrict__ zf,   // [B, HW, C] bf16
    const float* __restrict__ boxes,         // [B, N, 4]
    const float* __restrict__ Wt,            // [C, OUT_CH]
    const float* __restrict__ bias,          // [OUT_CH]
    float* __restrict__ out)                 // [B*N, OUT_CH]
{
  int bid = blockIdx.x;                    // 0..1023
  int img = (bid & 7) | ((bid >> 9) << 3); // image -> XCD class
  int roi = img * N_ + ((bid >> 3) & 63);
  int t   = threadIdx.x;
  int wv  = t >> 6;        // wave 0..7
  int co  = (t & 63) << 1; // channel pair offset

  float4 bx = ((const float4*)boxes)[roi];
  float x1 = bx.x * SCALE_ - 0.5f;
  float y1 = bx.y * SCALE_ - 0.5f;
  float roi_w = bx.z * SCALE_ - 0.5f - x1;
  float roi_h = bx.w * SCALE_ - 0.5f - y1;
  float gwf = fminf(fmaxf(ceilf(roi_w), 1.0f), (float)MAX_GRID_);
  float ghf = fminf(fmaxf(ceilf(roi_h), 1.0f), (float)MAX_GRID_);
  int gw = (int)gwf;
  int gh = (int)ghf;
  float stepx = roi_w / gwf;
  float stepy = roi_h / ghf;

  const unsigned short* zb = zf + (size_t)img * (HW_ * C_);

  float acc0 = 0.0f, acc1 = 0.0f;
  for (int gy = wv; gy < gh; gy += 8) {
    float sy = y1 + ((float)gy + 0.5f) * stepy;
    float wy = (sy > -1.0f && sy < (float)H_) ? 1.0f : 0.0f;
    float cy = fmaxf(sy, 0.0f);
    int yl = (int)cy;
    yl = yl < (H_ - 1) ? yl : (H_ - 1);
    int yh = (yl + 1) < (H_ - 1) ? (yl + 1) : (H_ - 1);
    if (yl >= H_ - 1) cy = (float)yl;
    float fy = cy - (float)yl;
    float hy = 1.0f - fy;
    const unsigned short* rowl = zb + (size_t)yl * W_ * C_ + co;
    const unsigned short* rowh = zb + (size_t)yh * W_ * C_ + co;

    for (int gx = 0; gx < gw; ++gx) {
      float sx = x1 + ((float)gx + 0.5f) * stepx;
      float wx = (sx > -1.0f && sx < (float)W_) ? 1.0f : 0.0f;
      float cx = fmaxf(sx, 0.0f);
      int xl = (int)cx;
      xl = xl < (W_ - 1) ? xl : (W_ - 1);
      int xh = (xl + 1) < (W_ - 1) ? (xl + 1) : (W_ - 1);
      if (xl >= W_ - 1) cx = (float)xl;
      float fx = cx - (float)xl;
      float hx = 1.0f - fx;

      float m   = wy * wx;
      float w11 = hy * hx * m, w12 = hy * fx * m;
      float w21 = fy * hx * m, w22 = fy * fx * m;
      unsigned int v11 = *(const unsigned int*)(rowl + (xl << 7));
      unsigned int v12 = *(const unsigned int*)(rowl + (xh << 7));
      unsigned int v21 = *(const unsigned int*)(rowh + (xl << 7));
      unsigned int v22 = *(const unsigned int*)(rowh + (xh << 7));

      acc0 += w11 * __uint_as_float(v11 << 16)
            + w12 * __uint_as_float(v12 << 16)
            + w21 * __uint_as_float(v21 << 16)
            + w22 * __uint_as_float(v22 << 16);
      acc1 += w11 * __uint_as_float(v11 & 0xffff0000u)
            + w12 * __uint_as_float(v12 & 0xffff0000u)
            + w21 * __uint_as_float(v21 & 0xffff0000u)
            + w22 * __uint_as_float(v22 & 0xffff0000u);
    }
  }

  __shared__ float red[8][128];
  __shared__ float feat[128];
  __shared__ float lin[2][256];
  red[wv][co]     = acc0;
  red[wv][co + 1] = acc1;
  __syncthreads();
  if (t < 128) {
    float s = (red[0][t] + red[1][t]) + (red[2][t] + red[3][t])
            + (red[4][t] + red[5][t]) + (red[6][t] + red[7][t]);
    feat[t] = s * (1.0f / (ghf * gwf));
  }
  __syncthreads();

  // Linear, split-K over 512 threads: half h sums k in [h*64, h*64+64)
  int oc   = t & 255;
  int half = t >> 8;
  const float* wp = Wt + (size_t)(half * 64) * OUT_CH_ + oc;
  const float* fp = feat + half * 64;
  float a = 0.0f;
#pragma unroll 8
  for (int k = 0; k < 64; ++k)
    a += fp[k] * wp[(size_t)k * OUT_CH_];
  lin[half][oc] = a;
  __syncthreads();
  if (t < 256)
    out[(size_t)roi * OUT_CH_ + t] = lin[0][t] + lin[1][t] + bias[t];
}

extern "C" void kernel_launch(void* const* d_in, const int* in_sizes, int n_in,
                              void* d_out, int out_size, void* d_ws, size_t ws_size,
                              hipStream_t stream) {
  const float* z     = (const float*)d_in[0];  // [B,C,H,W]
  const float* boxes = (const float*)d_in[1];  // [B,N,4]
  const float* Wm    = (const float*)d_in[2];  // [OUT_CH,C]
  const float* bias  = (const float*)d_in[3];  // [OUT_CH]
  float* out = (float*)d_out;

  char* ws = (char*)d_ws;
  unsigned short* zf = (unsigned short*)ws;                  // 16.78 MB
  float* Wt = (float*)(ws + (size_t)B_ * HW_ * C_ * 2);      // 128 KB

  transpose_kernel<<<dim3(HW_ / 128, B_ + 1), 256, 0, stream>>>(z, Wm, zf, Wt);
  roi_fused_kernel<<<B_ * N_, 512, 0, stream>>>(zf, boxes, Wt, bias, out);
}